// Round 3
// baseline (300.898 us; speedup 1.0000x reference)
//
#include <hip/hip_runtime.h>
#include <hip/hip_bf16.h>

// CGCNN: B=16, N=1024, M=12, F=64, BF=128, 3 conv layers.
// R3: fused per-layer conv (bond GEMM + softmax/mean/BN/residual) with no
// core/filt materialization. A-frags global->reg, B-frags in registers
// (pre-swizzled to MFMA fragment order), epilogue via wave-private LDS dump.

#define BB 16
#define NN 1024
#define MM 12
#define FF 64
#define S_BN 0.99950037f    // 1/sqrt(1+1e-3)
#define CSTR 74             // csh row stride (bf16 elems)

typedef __attribute__((ext_vector_type(8))) short bf16x8;
typedef __attribute__((ext_vector_type(4))) float f32x4;

static __device__ __forceinline__ unsigned short f2bf(float f) {
    union { float f; unsigned u; } c; c.f = f;
    unsigned r = c.u + 0x7fff + ((c.u >> 16) & 1);   // RNE
    return (unsigned short)(r >> 16);
}
static __device__ __forceinline__ float bf2f(unsigned short s) {
    union { unsigned u; float f; } c; c.u = ((unsigned)s) << 16;
    return c.f;
}

// ---- fold BN-a into core weights (fp32, for atomproj rows 0..127) ----------
__global__ void fold_w(const float* __restrict__ cw, const float* __restrict__ cb,
                       const float* __restrict__ g,  const float* __restrict__ bab,
                       float* __restrict__ cwp, float* __restrict__ cbp) {
    int i = blockIdx.x * 256 + threadIdx.x;           // 3*256*64
    if (i >= 3 * 256 * 64) return;
    int f = i & 63;
    int l = i / (256 * 64);
    float gs = g[l * 64 + f] * S_BN;
    cwp[i] = cw[i] * gs;
    if (((i >> 6) & 255) == 0)
        cbp[l * 64 + f] = cb[l * 64 + f] * gs + bab[l * 64 + f];
}

// ---- weight panel in MFMA B-fragment order ---------------------------------
// wT2[(((l*4+kc)*5+ct)*64+lane)*8+j] = B[col=ct*16+(lane&15)][k=kc*32+(lane>>4)*8+j]
// col 0..63: folded core weights rows 128..255; col 64: filt rows 128..255; 65..79: 0
__global__ void prep_wT2(const float* __restrict__ cw, const float* __restrict__ g,
                         const float* __restrict__ fw, unsigned short* __restrict__ wT2) {
    int i = blockIdx.x * 256 + threadIdx.x;           // 3*4*5*64*8 = 30720
    if (i >= 30720) return;
    int j = i & 7;
    int t = i >> 3;
    int lane = t & 63;  t >>= 6;
    int ct = t % 5;     t /= 5;
    int kc = t & 3;
    int l  = t >> 2;
    int col = ct * 16 + (lane & 15);
    int k   = kc * 32 + (lane >> 4) * 8 + j;
    float v = 0.f;
    if (col < 64)       v = cw[(l * 256 + 128 + k) * 64 + col] * g[l * 64 + col] * S_BN;
    else if (col == 64) v = fw[l * 256 + 128 + k];
    wT2[i] = f2bf(v);
}

// ---- embedding gather ------------------------------------------------------
__global__ void embed_k(const int* __restrict__ at, const float* __restrict__ emb,
                        float* __restrict__ x) {
    int i = blockIdx.x * 256 + threadIdx.x;
    int f = i & 63;
    int bn = i >> 6;
    x[i] = emb[at[bn] * FF + f];
}

// ---- per-atom projections (unchanged from R2) ------------------------------
__global__ __launch_bounds__(256) void atomproj(
    const float* __restrict__ x, const float* __restrict__ cwp_l,
    const float* __restrict__ cbp_l, const float* __restrict__ fw_l,
    const float* __restrict__ fb_l,
    float* __restrict__ ys, float* __restrict__ yn,
    float* __restrict__ fs, float* __restrict__ fn) {
    __shared__ float wsh[128 * 64];
    __shared__ float xs[4][64];
    int tid = threadIdx.x, w = tid >> 6, lane = tid & 63;
    #pragma unroll
    for (int i = 0; i < 8; i++)
        ((float4*)wsh)[tid + 256 * i] = ((const float4*)cwp_l)[tid + 256 * i];
    float fw1 = fw_l[lane], fw2 = fw_l[64 + lane];
    float cb = cbp_l[lane], fbv = fb_l[0];
    __syncthreads();
    #pragma unroll 1
    for (int it = 0; it < 4; it++) {
        int row = (blockIdx.x * 4 + it) * 4 + w;
        float xl = x[(size_t)row * 64 + lane];
        xs[w][lane] = xl;
        float a1 = cb, a2 = 0.f;
        #pragma unroll 16
        for (int k = 0; k < 64; k++) {
            float xv = xs[w][k];
            a1 += xv * wsh[k * 64 + lane];
            a2 += xv * wsh[(64 + k) * 64 + lane];
        }
        ys[(size_t)row * 64 + lane] = a1;
        yn[(size_t)row * 64 + lane] = a2;
        float p1 = xl * fw1, p2 = xl * fw2;
        #pragma unroll
        for (int off = 32; off; off >>= 1) {
            p1 += __shfl_xor(p1, off, 64);
            p2 += __shfl_xor(p2, off, 64);
        }
        if (lane == 0) { fs[row] = p1 + fbv; fn[row] = p2; }
    }
}

// ---- fused conv layer: bond@W (MFMA) + softmax + mean + BN-b + residual ----
// tile = 16 atoms = 192 bond rows; wave handles 48 rows = 4 atoms; 2 tiles/block
__global__ __launch_bounds__(256, 2) void conv_fused(
    const float* __restrict__ bond, const unsigned short* __restrict__ wTl,
    const int* __restrict__ nbr, const float* __restrict__ x,
    const float* __restrict__ ys, const float* __restrict__ yn,
    const float* __restrict__ fs, const float* __restrict__ fn,
    const float* __restrict__ bbg, const float* __restrict__ bbb,
    float* __restrict__ xout) {
    __shared__ unsigned short csh[4][48 * CSTR];   // 28.4 KB core dump (bf16)
    __shared__ float fltw[4][48];                  // filt logits
    int tid = threadIdx.x, w = tid >> 6, lane = tid & 63;
    int mcol = lane & 15, q = lane >> 4;

    // B fragments in registers (20 frags = 80 VGPR), loaded once per block
    bf16x8 bw[4][5];
    #pragma unroll
    for (int kc = 0; kc < 4; kc++)
        #pragma unroll
        for (int ct = 0; ct < 5; ct++)
            bw[kc][ct] = *(const bf16x8*)(wTl + ((kc * 5 + ct) * 64 + lane) * 8);

    #pragma unroll 1
    for (int t = 0; t < 2; t++) {
        int tile = blockIdx.x * 2 + t;
        int rowbase = tile * 192 + w * 48;

        f32x4 acc[3][5];
        #pragma unroll
        for (int rt = 0; rt < 3; rt++)
            #pragma unroll
            for (int ct = 0; ct < 5; ct++)
                acc[rt][ct] = (f32x4){0.f, 0.f, 0.f, 0.f};

        #pragma unroll
        for (int kc = 0; kc < 4; kc++) {
            #pragma unroll
            for (int rt = 0; rt < 3; rt++) {
                const float* ap = bond + (size_t)(rowbase + rt * 16 + mcol) * 128
                                + kc * 32 + q * 8;
                float4 v0 = *(const float4*)ap;
                float4 v1 = *(const float4*)(ap + 4);
                bf16x8 af;
                af[0] = (short)f2bf(v0.x); af[1] = (short)f2bf(v0.y);
                af[2] = (short)f2bf(v0.z); af[3] = (short)f2bf(v0.w);
                af[4] = (short)f2bf(v1.x); af[5] = (short)f2bf(v1.y);
                af[6] = (short)f2bf(v1.z); af[7] = (short)f2bf(v1.w);
                #pragma unroll
                for (int ct = 0; ct < 5; ct++)
                    acc[rt][ct] = __builtin_amdgcn_mfma_f32_16x16x32_bf16(
                        af, bw[kc][ct], acc[rt][ct], 0, 0, 0);
            }
        }

        // dump C (row = rt*16 + q*4 + r, col = ct*16 + mcol) to wave-private LDS
        #pragma unroll
        for (int rt = 0; rt < 3; rt++)
            #pragma unroll
            for (int r = 0; r < 4; r++) {
                int row = rt * 16 + q * 4 + r;
                #pragma unroll
                for (int ct = 0; ct < 4; ct++)
                    csh[w][row * CSTR + ct * 16 + mcol] = f2bf(acc[rt][ct][r]);
                if (mcol == 0) fltw[w][row] = acc[rt][4][r];
            }
        __syncthreads();

        // epilogue: lane -> (atom a = q, cols f = ct*16 + mcol)
        int atom = tile * 16 + w * 4 + q;
        int base = (atom >> 10) << 10;               // batch offset in atoms
        int jv[MM]; float lg[MM];
        #pragma unroll
        for (int m = 0; m < MM; m++) jv[m] = nbr[atom * MM + m];
        float fsv = fs[atom];
        #pragma unroll
        for (int m = 0; m < MM; m++)
            lg[m] = fltw[w][q * MM + m] + fsv + fn[base + jv[m]];
        float mx = -1e30f;
        #pragma unroll
        for (int m = 0; m < MM; m++) mx = fmaxf(mx, lg[m]);
        float sme = 0.f;
        #pragma unroll
        for (int m = 0; m < MM; m++) { lg[m] = __expf(lg[m] - mx); sme += lg[m]; }
        float inv = 1.f / (12.f * sme);

        float ysv[4], sum[4] = {0.f, 0.f, 0.f, 0.f};
        #pragma unroll
        for (int ct = 0; ct < 4; ct++)
            ysv[ct] = ys[(size_t)atom * 64 + ct * 16 + mcol];
        #pragma unroll
        for (int m = 0; m < MM; m++) {
            const float* ynr = yn + (size_t)(base + jv[m]) * 64;
            int row = q * MM + m;
            #pragma unroll
            for (int ct = 0; ct < 4; ct++) {
                float c = bf2f(csh[w][row * CSTR + ct * 16 + mcol])
                        + ysv[ct] + ynr[ct * 16 + mcol];
                sum[ct] += lg[m] * fmaxf(c, 0.f);
            }
        }
        #pragma unroll
        for (int ct = 0; ct < 4; ct++) {
            int f = ct * 16 + mcol;
            float o = x[(size_t)atom * 64 + f] + bbg[f] * (sum[ct] * inv * S_BN) + bbb[f];
            xout[(size_t)atom * 64 + f] = fmaxf(o, 0.f);
        }
        __syncthreads();   // protect csh/fltw before next tile's dump
    }
}

// ---- pooling gather + dense + relu ----------------------------------------
__global__ __launch_bounds__(256) void final_k(
    const float* __restrict__ x, const int* __restrict__ tidx,
    const float* __restrict__ dw, const float* __restrict__ db,
    float* __restrict__ out) {
    __shared__ float xs[4][64];
    __shared__ float wsh[64 * 64];
    int tid = threadIdx.x;
    int w = tid >> 6, lane = tid & 63;
    const float4* src = (const float4*)dw;
    float4* dst = (float4*)wsh;
    #pragma unroll
    for (int i = 0; i < 4; i++) dst[tid + 256 * i] = src[tid + 256 * i];
    int row = blockIdx.x * 4 + w;
    int b = row >> 6;
    int t = tidx[row];
    float xv = x[((size_t)b * NN + t) * 64 + lane];
    xs[w][lane] = fmaxf(xv, 0.f);
    __syncthreads();
    float a = db[lane];
    #pragma unroll 16
    for (int k = 0; k < 64; k++) a += xs[w][k] * wsh[k * 64 + lane];
    out[row * 64 + lane] = fmaxf(a, 0.f);
}

extern "C" void kernel_launch(void* const* d_in, const int* in_sizes, int n_in,
                              void* d_out, int out_size, void* d_ws, size_t ws_size,
                              hipStream_t stream) {
    const int*   at   = (const int*)d_in[0];
    const float* bond = (const float*)d_in[1];
    const int*   nbr  = (const int*)d_in[2];
    const int*   tgt  = (const int*)d_in[3];
    const float* emb  = (const float*)d_in[4];
    const float* cw   = (const float*)d_in[5];
    const float* cb   = (const float*)d_in[6];
    const float* fw   = (const float*)d_in[7];
    const float* fb   = (const float*)d_in[8];
    const float* bag  = (const float*)d_in[9];
    const float* bab  = (const float*)d_in[10];
    const float* bbg  = (const float*)d_in[11];
    const float* bbb  = (const float*)d_in[12];
    const float* dw   = (const float*)d_in[13];
    const float* db   = (const float*)d_in[14];

    float* ws  = (float*)d_ws;
    float* xA  = ws;
    float* xB  = xA + (size_t)BB * NN * FF;
    float* cwp = xB + (size_t)BB * NN * FF;
    float* cbp = cwp + 3 * 256 * 64;
    float* ys  = cbp + 192;
    float* yn  = ys + (size_t)BB * NN * FF;
    float* fs  = yn + (size_t)BB * NN * FF;
    float* fn  = fs + (size_t)BB * NN;
    unsigned short* wT2 = (unsigned short*)(fn + (size_t)BB * NN);  // 30720 bf16
    // total ~17 MB

    fold_w<<<(3 * 256 * 64 + 255) / 256, 256, 0, stream>>>(cw, cb, bag, bab, cwp, cbp);
    prep_wT2<<<120, 256, 0, stream>>>(cw, bag, fw, wT2);
    embed_k<<<(BB * NN * FF) / 256, 256, 0, stream>>>(at, emb, xA);

    float* xin = xA;
    float* xout = xB;
    for (int l = 0; l < 3; l++) {
        atomproj<<<BB * NN / 16, 256, 0, stream>>>(
            xin, cwp + (size_t)l * 256 * 64, cbp + l * 64, fw + l * 256, fb + l,
            ys, yn, fs, fn);
        conv_fused<<<512, 256, 0, stream>>>(
            bond, wT2 + (size_t)l * 10240, nbr, xin,
            ys, yn, fs, fn, bbg + l * 64, bbb + l * 64, xout);
        float* t = xin; xin = xout; xout = t;
    }

    final_k<<<BB * 64 / 4, 256, 0, stream>>>(xin, tgt, dw, db, (float*)d_out);
}